// Round 1
// baseline (602.121 us; speedup 1.0000x reference)
//
#include <hip/hip_runtime.h>

#define B_TOT 4096
#define T_STEPS 512
#define IN 20
#define HID 51

typedef float f32x4 __attribute__((ext_vector_type(4)));
typedef short s16x8 __attribute__((ext_vector_type(8)));

__device__ __forceinline__ unsigned short f2bf(float f) {
    unsigned int u = __float_as_uint(f);
    unsigned int r = (u + 0x7fffu + ((u >> 16) & 1u)) >> 16;
    return (unsigned short)r;
}

__device__ __forceinline__ float fast_rcp(float x) { return __builtin_amdgcn_rcpf(x); }
// sigmoid(x) = 1/(1+e^-x); exp overflow -> inf -> rcp -> 0 (correct saturation)
__device__ __forceinline__ float sigf(float x) { return fast_rcp(1.0f + __expf(-x)); }
// tanh(x) = 1 - 2/(1+e^{2x}); saturates correctly at +-1
__device__ __forceinline__ float tanh_(float x) { return 1.0f - 2.0f * fast_rcp(1.0f + __expf(2.0f * x)); }

__global__ __launch_bounds__(256, 1)
void lstm_fused(const float* __restrict__ x,
                const float* __restrict__ Wih1, const float* __restrict__ Whh1,
                const float* __restrict__ bih1, const float* __restrict__ bhh1,
                const float* __restrict__ Wih2, const float* __restrict__ Whh2,
                const float* __restrict__ bih2, const float* __restrict__ bhh2,
                const float* __restrict__ Wmu,  const float* __restrict__ bmu,
                const float* __restrict__ Wlv,  const float* __restrict__ blv,
                float* __restrict__ out)
{
    // A-operand staging, pre-swizzled to fragment order: [buf][ks][lane][j]
    // element (batch b, k): ks=k>>5, lane=(((k>>3)&3)<<4)|b, j=k&7
    __shared__ __align__(16) unsigned short vA[2][3][64][8];
    // linear h1 copy for the layer-2 (VALU) phase, double buffered
    __shared__ __align__(16) float hL[2][16][68];

    const int tid  = threadIdx.x;
    const int lane = tid & 63;
    const int w    = tid >> 6;      // wave id == unit group
    const int bidx = blockIdx.x;

    // ---- B fragments (weights), gathered once. B[k][n]: n=lane&15, k=(lane>>4)*8+j ----
    const int nu = (w << 4) + (lane & 15);   // unit column 0..63 (pad >=51 -> zero weights)
    s16x8 frag[4][3];
    #pragma unroll
    for (int gate = 0; gate < 4; ++gate) {
        #pragma unroll
        for (int ks = 0; ks < 3; ++ks) {
            s16x8 f;
            #pragma unroll
            for (int j = 0; j < 8; ++j) {
                int k = ks * 32 + ((lane >> 4) << 3) + j;
                float v = 0.0f;
                if (nu < HID) {
                    int row = gate * HID + nu;
                    if (k < IN) v = Wih1[row * IN + k];
                    else if (k >= 32) {
                        int ku = k - 32;
                        if (ku < HID) v = Whh1[row * HID + ku];
                    }
                }
                f[j] = (short)f2bf(v);
            }
            frag[gate][ks] = f;
        }
    }
    float bias[4];
    #pragma unroll
    for (int gate = 0; gate < 4; ++gate)
        bias[gate] = (nu < HID) ? (bih1[gate * HID + nu] + bhh1[gate * HID + nu]) : 0.0f;

    // ---- layer-2 setup: lane = (kc<<4) | (bl<<2) | r ----
    const int r2  = lane & 3;            // gate row of layer 2
    const int kc  = lane >> 4;           // K-chunk 0..3 (16 wide)
    const int bl2 = (lane >> 2) & 3;
    const int b2  = (w << 2) + bl2;      // local batch 0..15
    float w2c[16];
    #pragma unroll
    for (int i = 0; i < 16; ++i) {
        int m = kc * 16 + i;
        w2c[i] = (m < HID) ? Wih2[r2 * HID + m] : 0.0f;
    }
    const float whh2r = Whh2[r2];
    const float b2cr  = bih2[r2] + bhh2[r2];

    // ---- x loader setup: 320 elems/step, thread handles e=tid and (tid<64) e=256+tid ----
    const int bl0 = tid / IN,        m0 = tid % IN;
    const int bl1 = (256 + tid) / IN, m1 = (256 + tid) % IN;
    const float* xp0 = x + ((size_t)(bidx * 16 + bl0) * T_STEPS) * IN + m0;
    const float* xp1 = x + ((size_t)(bidx * 16 + bl1) * T_STEPS) * IN + m1;
    const int q0 = m0 >> 3, j0 = m0 & 7;
    const int q1 = m1 >> 3, j1 = m1 & 7;

    // ---- init: zero ALL of vA (stale LDS could hold NaN patterns; NaN*0=NaN) ----
    {
        unsigned short* vz = &vA[0][0][0][0];
        for (int i = tid; i < 2 * 3 * 64 * 8; i += 256) vz[i] = 0;
    }
    __syncthreads();
    // x_0 into vA[0]
    vA[0][0][q0 * 16 + bl0][j0] = f2bf(xp0[0]);
    if (tid < 64) vA[0][0][q1 * 16 + bl1][j1] = f2bf(xp1[0]);
    __syncthreads();

    float c1r[4] = {0.f, 0.f, 0.f, 0.f};
    float c2p = 0.f, h2p = 0.f, sum2 = 0.f;

    for (int t = 0; t < T_STEPS; ++t) {
        const int p  = t & 1;
        const int pn = p ^ 1;

        // prefetch x_{t+1}
        const int t1 = (t < T_STEPS - 1) ? t + 1 : t;
        float xr0 = xp0[t1 * IN];
        float xr1 = 0.0f;
        if (tid < 64) xr1 = xp1[t1 * IN];

        // A fragments: A[m=lane&15][k=(lane>>4)*8+j]
        s16x8 a0 = *(const s16x8*)&vA[p][0][lane][0];
        s16x8 a1 = *(const s16x8*)&vA[p][1][lane][0];
        s16x8 a2 = *(const s16x8*)&vA[p][2][lane][0];

        f32x4 acc[4];
        #pragma unroll
        for (int gate = 0; gate < 4; ++gate) {
            f32x4 a = {0.f, 0.f, 0.f, 0.f};
            a = __builtin_amdgcn_mfma_f32_16x16x32_bf16(a0, frag[gate][0], a, 0, 0, 0);
            a = __builtin_amdgcn_mfma_f32_16x16x32_bf16(a1, frag[gate][1], a, 0, 0, 0);
            a = __builtin_amdgcn_mfma_f32_16x16x32_bf16(a2, frag[gate][2], a, 0, 0, 0);
            acc[gate] = a;
        }

        // ---- layer 2 for step t-1 (pipelined; reads hL[(t-1)&1] = hL[pn]) ----
        if (t > 0) {
            const float* hrow = &hL[pn][b2][0];
            float acc2 = 0.0f;
            #pragma unroll
            for (int i4 = 0; i4 < 4; ++i4) {
                const float4 hv = *(const float4*)&hrow[kc * 16 + i4 * 4];
                acc2 += w2c[i4 * 4 + 0] * hv.x + w2c[i4 * 4 + 1] * hv.y
                      + w2c[i4 * 4 + 2] * hv.z + w2c[i4 * 4 + 3] * hv.w;
            }
            acc2 += __shfl_xor(acc2, 16);
            acc2 += __shfl_xor(acc2, 32);
            float g2 = acc2 + b2cr + whh2r * h2p;
            int base = lane & ~3;
            float gi2 = __shfl(g2, base + 0);
            float gf2 = __shfl(g2, base + 1);
            float gg2 = __shfl(g2, base + 2);
            float go2 = __shfl(g2, base + 3);
            float c2n = sigf(gf2) * c2p + sigf(gi2) * tanh_(gg2);
            c2p = c2n;
            h2p = sigf(go2) * tanh_(c2n);
            sum2 += h2p;
        }

        // ---- layer-1 epilogue: lane owns unit nu for 4 batches ----
        #pragma unroll
        for (int r = 0; r < 4; ++r) {
            float gi = acc[0][r] + bias[0];
            float gf = acc[1][r] + bias[1];
            float gg = acc[2][r] + bias[2];
            float go = acc[3][r] + bias[3];
            float si = sigf(gi), sf = sigf(gf), so = sigf(go);
            float tg = tanh_(gg);
            float c  = sf * c1r[r] + si * tg;
            c1r[r] = c;
            float h  = so * tanh_(c);
            int b = ((lane >> 4) << 2) + r;
            hL[p][b][nu] = h;                       // for layer 2 (next iter)
            int k = 32 + nu;                        // h1 slot in next A buffer
            vA[pn][k >> 5][(((k >> 3) & 3) << 4) + b][k & 7] = f2bf(h);
        }

        // x_{t+1} into next A buffer
        vA[pn][0][q0 * 16 + bl0][j0] = f2bf(xr0);
        if (tid < 64) vA[pn][0][q1 * 16 + bl1][j1] = f2bf(xr1);

        __syncthreads();
    }

    // ---- final layer-2 step (t = 511; h1 is in hL[1]) ----
    {
        const float* hrow = &hL[1][b2][0];
        float acc2 = 0.0f;
        #pragma unroll
        for (int i4 = 0; i4 < 4; ++i4) {
            const float4 hv = *(const float4*)&hrow[kc * 16 + i4 * 4];
            acc2 += w2c[i4 * 4 + 0] * hv.x + w2c[i4 * 4 + 1] * hv.y
                  + w2c[i4 * 4 + 2] * hv.z + w2c[i4 * 4 + 3] * hv.w;
        }
        acc2 += __shfl_xor(acc2, 16);
        acc2 += __shfl_xor(acc2, 32);
        float g2 = acc2 + b2cr + whh2r * h2p;
        int base = lane & ~3;
        float gi2 = __shfl(g2, base + 0);
        float gf2 = __shfl(g2, base + 1);
        float gg2 = __shfl(g2, base + 2);
        float go2 = __shfl(g2, base + 3);
        float c2n = sigf(gf2) * c2p + sigf(gi2) * tanh_(gg2);
        h2p = sigf(go2) * tanh_(c2n);
        sum2 += h2p;
    }

    // ---- head + output: (lower, mu, upper, log_var) concat flat ----
    if (lane < 16 && (lane & 3) == 0) {
        int bg = bidx * 16 + (w << 2) + (lane >> 2);
        float agg = sum2 * (1.0f / 512.0f);
        float mu  = Wmu[0] * agg + bmu[0];
        float lv  = Wlv[0] * agg + blv[0];
        float sg  = __expf(0.5f * lv);
        out[bg]             = mu - 1.96f * sg;
        out[B_TOT + bg]     = mu;
        out[2 * B_TOT + bg] = mu + 1.96f * sg;
        out[3 * B_TOT + bg] = lv;
    }
}

extern "C" void kernel_launch(void* const* d_in, const int* in_sizes, int n_in,
                              void* d_out, int out_size, void* d_ws, size_t ws_size,
                              hipStream_t stream) {
    const float* x    = (const float*)d_in[0];
    const float* Wih1 = (const float*)d_in[1];
    const float* Whh1 = (const float*)d_in[2];
    const float* bih1 = (const float*)d_in[3];
    const float* bhh1 = (const float*)d_in[4];
    const float* Wih2 = (const float*)d_in[5];
    const float* Whh2 = (const float*)d_in[6];
    const float* bih2 = (const float*)d_in[7];
    const float* bhh2 = (const float*)d_in[8];
    const float* Wmu  = (const float*)d_in[9];
    const float* bmu  = (const float*)d_in[10];
    const float* Wlv  = (const float*)d_in[11];
    const float* blv  = (const float*)d_in[12];
    float* out = (float*)d_out;

    lstm_fused<<<dim3(B_TOT / 16), dim3(256), 0, stream>>>(
        x, Wih1, Whh1, bih1, bhh1, Wih2, Whh2, bih2, bhh2, Wmu, bmu, Wlv, blv, out);
}

// Round 2
// 504.982 us; speedup vs baseline: 1.1924x; 1.1924x over previous
//
#include <hip/hip_runtime.h>

#define B_TOT 4096
#define T_STEPS 512
#define IN 20
#define HID 51

typedef float f32x4 __attribute__((ext_vector_type(4)));
typedef short s16x8 __attribute__((ext_vector_type(8)));

__device__ __forceinline__ unsigned short f2bf(float f) {
    unsigned int u = __float_as_uint(f);
    unsigned int r = (u + 0x7fffu + ((u >> 16) & 1u)) >> 16;
    return (unsigned short)r;
}

__device__ __forceinline__ float fast_rcp(float x) { return __builtin_amdgcn_rcpf(x); }
__device__ __forceinline__ float sigf(float x) { return fast_rcp(1.0f + __expf(-x)); }
__device__ __forceinline__ float tanh_(float x) { return 1.0f - 2.0f * fast_rcp(1.0f + __expf(2.0f * x)); }

// Tiles: 13 layer-1 tiles (rows = unit_local*4 + gate, units 4t..4t+3; 52 >= 51 units)
//        + tile 13 = layer-2 (rows 0..3 = Wih2 gate rows over the h1 K-region).
// Orientation: A = weights (M = unit-gate rows), B = staged data (N = 16 batches).
// D layout: col=lane&15=batch, row=(lane>>4)*4+reg  ->  lane owns ALL 4 gates of
// one (unit,batch) in its 4 accum regs: nonlinearity is fully lane-local.

__global__ __launch_bounds__(512, 2)
void lstm_fused(const float* __restrict__ x,
                const float* __restrict__ Wih1, const float* __restrict__ Whh1,
                const float* __restrict__ bih1, const float* __restrict__ bhh1,
                const float* __restrict__ Wih2, const float* __restrict__ Whh2,
                const float* __restrict__ bih2, const float* __restrict__ bhh2,
                const float* __restrict__ Wmu,  const float* __restrict__ bmu,
                const float* __restrict__ Wlv,  const float* __restrict__ blv,
                float* __restrict__ out)
{
    // B-operand staging, fragment order: [buf][ks][(((k>>3)&3)<<4)|batch][k&7]
    __shared__ __align__(16) unsigned short vA[2][3][64][8];

    const int tid  = threadIdx.x;
    const int lane = tid & 63;
    const int w    = tid >> 6;      // 0..7
    const int bidx = blockIdx.x;

    // ---- tile assignment: waves 0..5 -> {2w, 2w+1}; wave 6 -> {12}; wave 7 -> {13} ----
    const int ntile = (w < 6) ? 2 : 1;
    int tiles[2];
    tiles[0] = (w < 6) ? 2 * w : (w == 6 ? 12 : 13);
    tiles[1] = (w < 6) ? 2 * w + 1 : -1;
    const bool isL2 = (tiles[0] == 13);

    // ---- gather A-operand weight fragments: A[m=lane&15][k=(lane>>4)*8+j] ----
    s16x8 wfrag[2][3];
    float bias[2][4];
    #pragma unroll
    for (int ti = 0; ti < 2; ++ti) {
        const int tau = tiles[ti];
        const int m = lane & 15;
        #pragma unroll
        for (int ks = 0; ks < 3; ++ks) {
            s16x8 f;
            #pragma unroll
            for (int j = 0; j < 8; ++j) {
                int k = ks * 32 + ((lane >> 4) << 3) + j;
                float v = 0.0f;
                if (tau >= 0) {
                    if (tau < 13) {
                        int g = m & 3, unit = tau * 4 + (m >> 2);
                        if (unit < HID) {
                            int row = g * HID + unit;
                            if (k < IN) v = Wih1[row * IN + k];
                            else if (k >= 32 && k < 32 + HID) v = Whh1[row * HID + (k - 32)];
                        }
                    } else {  // layer-2 tile: rows 0..3 = Wih2 gate rows
                        if (m < 4 && k >= 32 && k < 32 + HID) v = Wih2[m * HID + (k - 32)];
                    }
                }
                f[j] = (short)f2bf(v);
            }
            wfrag[ti][ks] = f;
        }
        // bias in D layout: unit = tau*4 + (lane>>4), gate = reg index
        #pragma unroll
        for (int r = 0; r < 4; ++r) {
            float bv = 0.0f;
            if (tau >= 0 && tau < 13) {
                int unit = tau * 4 + (lane >> 4);
                if (unit < HID) bv = bih1[r * HID + unit] + bhh1[r * HID + unit];
            }
            bias[ti][r] = bv;
        }
    }

    // layer-2 scalar constants (tiny; load in all waves)
    float whh2g[4], b2g[4];
    #pragma unroll
    for (int r = 0; r < 4; ++r) { whh2g[r] = Whh2[r]; b2g[r] = bih2[r] + bhh2[r]; }

    // ---- x stager: 320 elems/step, tid<320 handles one (batch, feature) ----
    const bool xs = (tid < 16 * IN);
    const int xb = tid / IN, xm = tid % IN;
    const float* xp = x + ((size_t)(bidx * 16 + xb) * T_STEPS) * IN + xm;
    const int xrow = ((xm >> 3) & 3) * 16 + xb;
    const int xj = xm & 7;

    // ---- zero-init both staging buffers (pads must be exact 0) ----
    {
        unsigned short* vz = &vA[0][0][0][0];
        for (int i = tid; i < 2 * 3 * 64 * 8; i += 512) vz[i] = 0;
    }
    __syncthreads();
    if (xs) vA[0][0][xrow][xj] = f2bf(xp[0]);
    __syncthreads();

    float c1[2] = {0.f, 0.f};
    float c2p = 0.f, h2p = 0.f, sum2 = 0.f;

    for (int t = 0; t < T_STEPS; ++t) {
        const int p  = t & 1;
        const int pn = p ^ 1;

        // prefetch x_{t+1}
        const int t1 = (t < T_STEPS - 1) ? t + 1 : t;
        float xr = 0.0f;
        if (xs) xr = xp[(size_t)t1 * IN];

        // B fragments (shared across all tiles): B[k][n=batch]
        s16x8 bf0 = *(const s16x8*)&vA[p][0][lane][0];
        s16x8 bf1 = *(const s16x8*)&vA[p][1][lane][0];
        s16x8 bf2 = *(const s16x8*)&vA[p][2][lane][0];

        f32x4 acc[2];
        {
            f32x4 a = {0.f, 0.f, 0.f, 0.f};
            a = __builtin_amdgcn_mfma_f32_16x16x32_bf16(wfrag[0][0], bf0, a, 0, 0, 0);
            a = __builtin_amdgcn_mfma_f32_16x16x32_bf16(wfrag[0][1], bf1, a, 0, 0, 0);
            a = __builtin_amdgcn_mfma_f32_16x16x32_bf16(wfrag[0][2], bf2, a, 0, 0, 0);
            acc[0] = a;
        }
        if (ntile == 2) {
            f32x4 a = {0.f, 0.f, 0.f, 0.f};
            a = __builtin_amdgcn_mfma_f32_16x16x32_bf16(wfrag[1][0], bf0, a, 0, 0, 0);
            a = __builtin_amdgcn_mfma_f32_16x16x32_bf16(wfrag[1][1], bf1, a, 0, 0, 0);
            a = __builtin_amdgcn_mfma_f32_16x16x32_bf16(wfrag[1][2], bf2, a, 0, 0, 0);
            acc[1] = a;
        }

        // ---- layer-1 epilogue: lane-local nonlinearity, one (unit,batch) per tile ----
        #pragma unroll
        for (int ti = 0; ti < 2; ++ti) {
            if (ti < ntile && tiles[ti] < 13) {
                float gi = acc[ti][0] + bias[ti][0];
                float gf = acc[ti][1] + bias[ti][1];
                float gg = acc[ti][2] + bias[ti][2];
                float go = acc[ti][3] + bias[ti][3];
                float c  = sigf(gf) * c1[ti] + sigf(gi) * tanh_(gg);
                c1[ti]   = c;
                float h  = sigf(go) * tanh_(c);
                int unit = tiles[ti] * 4 + (lane >> 4);
                int k    = 32 + unit;
                int b    = lane & 15;
                vA[pn][k >> 5][(((k >> 3) & 3) << 4) + b][k & 7] = f2bf(h);
            }
        }

        // ---- layer-2 (wave with tile 13): result corresponds to step t-1 ----
        if (isL2 && t > 0 && lane < 16) {
            float pi = acc[0][0] + b2g[0] + whh2g[0] * h2p;
            float pf = acc[0][1] + b2g[1] + whh2g[1] * h2p;
            float pg = acc[0][2] + b2g[2] + whh2g[2] * h2p;
            float po = acc[0][3] + b2g[3] + whh2g[3] * h2p;
            float c2 = sigf(pf) * c2p + sigf(pi) * tanh_(pg);
            c2p = c2;
            h2p = sigf(po) * tanh_(c2);
            sum2 += h2p;
        }

        // stage x_{t+1}
        if (xs) vA[pn][0][xrow][xj] = f2bf(xr);

        __syncthreads();
    }

    // ---- final layer-2 step (t=511): h1_511 sits in vA[0] ----
    if (isL2) {
        s16x8 bf0 = *(const s16x8*)&vA[0][0][lane][0];
        s16x8 bf1 = *(const s16x8*)&vA[0][1][lane][0];
        s16x8 bf2 = *(const s16x8*)&vA[0][2][lane][0];
        f32x4 a = {0.f, 0.f, 0.f, 0.f};
        a = __builtin_amdgcn_mfma_f32_16x16x32_bf16(wfrag[0][0], bf0, a, 0, 0, 0);
        a = __builtin_amdgcn_mfma_f32_16x16x32_bf16(wfrag[0][1], bf1, a, 0, 0, 0);
        a = __builtin_amdgcn_mfma_f32_16x16x32_bf16(wfrag[0][2], bf2, a, 0, 0, 0);
        if (lane < 16) {
            float pi = a[0] + b2g[0] + whh2g[0] * h2p;
            float pf = a[1] + b2g[1] + whh2g[1] * h2p;
            float pg = a[2] + b2g[2] + whh2g[2] * h2p;
            float po = a[3] + b2g[3] + whh2g[3] * h2p;
            float c2 = sigf(pf) * c2p + sigf(pi) * tanh_(pg);
            h2p = sigf(po) * tanh_(c2);
            sum2 += h2p;

            // ---- head: (lower, mu, upper, log_var) ----
            float agg = sum2 * (1.0f / 512.0f);
            float mu  = Wmu[0] * agg + bmu[0];
            float lv  = Wlv[0] * agg + blv[0];
            float sg  = __expf(0.5f * lv);
            int bg = bidx * 16 + lane;
            out[bg]             = mu - 1.96f * sg;
            out[B_TOT + bg]     = mu;
            out[2 * B_TOT + bg] = mu + 1.96f * sg;
            out[3 * B_TOT + bg] = lv;
        }
    }
}

extern "C" void kernel_launch(void* const* d_in, const int* in_sizes, int n_in,
                              void* d_out, int out_size, void* d_ws, size_t ws_size,
                              hipStream_t stream) {
    const float* x    = (const float*)d_in[0];
    const float* Wih1 = (const float*)d_in[1];
    const float* Whh1 = (const float*)d_in[2];
    const float* bih1 = (const float*)d_in[3];
    const float* bhh1 = (const float*)d_in[4];
    const float* Wih2 = (const float*)d_in[5];
    const float* Whh2 = (const float*)d_in[6];
    const float* bih2 = (const float*)d_in[7];
    const float* bhh2 = (const float*)d_in[8];
    const float* Wmu  = (const float*)d_in[9];
    const float* bmu  = (const float*)d_in[10];
    const float* Wlv  = (const float*)d_in[11];
    const float* blv  = (const float*)d_in[12];
    float* out = (float*)d_out;

    lstm_fused<<<dim3(B_TOT / 16), dim3(512), 0, stream>>>(
        x, Wih1, Whh1, bih1, bhh1, Wih2, Whh2, bih2, bhh2, Wmu, bmu, Wlv, blv, out);
}